// Round 3
// baseline (369.428 us; speedup 1.0000x reference)
//
#include <hip/hip_runtime.h>
#include <hip/hip_bf16.h>

// GCN v13 — feature-slabbed gather (2 passes x 32 features) + MFMA matvec.
//   Theory (r13): gather was L2-capacity-bound — per-XCD working set 12.8 MB
//   vs 4 MB L2 -> 33% hit (measured FETCH 156 MB = 136 MB gather misses).
//   Fix: g/a stored as [2][n][32] bf16 slabs; gather runs 2 passes, each on
//   a 6.4 MB slab (-> ~62% hit). Gather widened to v8s: 16 edges/VMEM inst,
//   shfl_xor butterfly reduce. Streams (rows4, a-writes) non-temporal.
//   k_mat reads A-frags from slab bases (K-split at 32 == slab boundary).
//   Build (4 merged dispatches): unchanged.
//   (r15 resubmit: rounds 1-2 were container-acquisition flakes, no data.
//    Source audited twice for device-hang mechanisms: none found.)

#define FDIM 64
#define NPART 8
#define GPB 64
#define NB 256
#define BW 512
#define MAXP 1024
#define GPLIN 1024

typedef __hip_bfloat16 bf16;
typedef short v8s __attribute__((ext_vector_type(8)));
typedef float v4f __attribute__((ext_vector_type(4)));

static __device__ __forceinline__ float b2f(short s) {
    union { unsigned u; float f; } v;
    v.u = ((unsigned)(unsigned short)s) << 16;
    return v.f;
}
static __device__ __forceinline__ short f2b(float f) {
    bf16 b = __float2bfloat16(f);
    return *(short*)&b;
}

// --- dispatch 1: deg partial histograms ∥ coarse col histogram ---
__global__ void k_h(const int* __restrict__ row, const int* __restrict__ col,
                    unsigned* __restrict__ part, int* __restrict__ M,
                    int E, int n, int psize, int P, int CH) {
    __shared__ unsigned sm[12512];
    int t = threadIdx.x, b = blockIdx.x;
    if (b < NPART * GPB) {
        int p = b >> 6, g = b & 63;
        int base = p * psize;
        int lim = n - base; if (lim > psize) lim = psize;
        for (int i = t; i < lim; i += 256) sm[i] = 0u;
        __syncthreads();
        for (int e = g * 256 + t; e < E; e += GPB * 256) {
            int r = row[e] - base;
            if ((unsigned)r < (unsigned)lim) atomicAdd(&sm[r], 1u);
        }
        __syncthreads();
        unsigned* dst = part + ((size_t)p * GPB + g) * psize;
        for (int i = t; i < lim; i += 256) dst[i] = sm[i];
    } else {
        int cb = b - NPART * GPB;
        int* h = (int*)sm;
        for (int i = t; i < P; i += 256) h[i] = 0;
        __syncthreads();
        int s = cb * CH, e = min(s + CH, E);
        for (int i = s + t; i < e; i += 256)
            atomicAdd(&h[col[i] >> 9], 1);
        __syncthreads();
        for (int p = t; p < P; p += 256) M[p * NB + cb] = h[p];
    }
}

// --- dispatch 2: dis ∥ scan pass 1 ---
__global__ void k_ds1(const unsigned* __restrict__ part, float* __restrict__ dis,
                      int* __restrict__ M, int* __restrict__ bsum,
                      int n, int psize, int ndis, int P) {
    __shared__ int sc[256];
    int t = threadIdx.x, b = blockIdx.x;
    if (b < ndis) {
        int i = b * 256 + t;
        if (i >= n) return;
        int p = i / psize, loc = i - p * psize;
        const unsigned* src = part + (size_t)p * GPB * psize + loc;
        unsigned s = 0;
        #pragma unroll 8
        for (int g = 0; g < GPB; ++g) s += src[(size_t)g * psize];
        dis[i] = rsqrtf((float)s + 1.0f);
    } else {
        int sb = b - ndis;
        int i = sb * 256 + t;
        int v = M[i];
        sc[t] = v;
        __syncthreads();
        for (int d = 1; d < 256; d <<= 1) {
            int u = (t >= d) ? sc[t - d] : 0;
            __syncthreads(); sc[t] += u; __syncthreads();
        }
        M[i] = sc[t] - v;
        if (t == 255) bsum[sb] = sc[255];
    }
}

// --- dispatch 3: coarse scatter (inline bsum scan) ---
__global__ void k_csc(const int* __restrict__ row, const int* __restrict__ col,
                      const int* __restrict__ M, const int* __restrict__ bsum,
                      int* __restrict__ s4, int E, int CH, int P) {
    __shared__ int sc[256];
    __shared__ int bs[256];
    __shared__ int cur[MAXP];
    int t = threadIdx.x, b = blockIdx.x;
    int v = (t < P) ? bsum[t] : 0;
    sc[t] = v;
    __syncthreads();
    for (int d = 1; d < 256; d <<= 1) {
        int u = (t >= d) ? sc[t - d] : 0;
        __syncthreads(); sc[t] += u; __syncthreads();
    }
    bs[t] = sc[t] - v;
    __syncthreads();
    for (int p = t; p < P; p += 256) cur[p] = bs[p] + M[p * NB + b];
    __syncthreads();
    int s = b * CH, e = min(s + CH, E);
    for (int i = s + t; i < e; i += 256) {
        int r = row[i], c = col[i];
        int pos = atomicAdd(&cur[c >> 9], 1);
        s4[pos] = (r << 9) | (c & 511);
    }
}

// --- dispatch 4: fine sort (blocks < P) ∥ k_linc (blocks >= P) ---
__global__ __launch_bounds__(256, 4)
void k_fl(const int* __restrict__ s4, const int* __restrict__ M,
          const int* __restrict__ bsum, int* __restrict__ rows4,
          int* __restrict__ off,
          const float* __restrict__ x, const float* __restrict__ feat,
          const float* __restrict__ W, const float* __restrict__ bvec,
          const float* __restrict__ dis, bf16* __restrict__ g1,
          int n, int E, int P) {
    __shared__ int sc[256];
    __shared__ int bs[256];
    __shared__ int hist[BW];
    __shared__ int loff[BW];
    __shared__ int tmp[256];
    __shared__ float sIn[4][FDIM];
    int t = threadIdx.x, b = blockIdx.x;
    if (b < P) {
        int v = (t < P) ? bsum[t] : 0;
        sc[t] = v;
        __syncthreads();
        for (int d = 1; d < 256; d <<= 1) {
            int u = (t >= d) ? sc[t - d] : 0;
            __syncthreads(); sc[t] += u; __syncthreads();
        }
        bs[t] = sc[t] - v;
        __syncthreads();
        int gs = bs[b];
        int ge = gs + bsum[b];
        int c0 = b << 9;
        int lim = n - c0; if (lim > BW) lim = BW;
        hist[2 * t] = 0; hist[2 * t + 1] = 0;
        __syncthreads();
        for (int i = gs + t; i < ge; i += 256)
            atomicAdd(&hist[s4[i] & 511], 1);
        __syncthreads();
        int s0 = hist[2 * t], s1v = hist[2 * t + 1];
        int ps = s0 + s1v;
        tmp[t] = ps;
        __syncthreads();
        for (int d = 1; d < 256; d <<= 1) {
            int u = (t >= d) ? tmp[t - d] : 0;
            __syncthreads(); tmp[t] += u; __syncthreads();
        }
        int ex = tmp[t] - ps;
        loff[2 * t] = ex;
        loff[2 * t + 1] = ex + s0;
        __syncthreads();
        for (int i = t; i < lim; i += 256) off[c0 + i] = gs + loff[i];
        if (b == P - 1 && t == 0) off[n] = E;
        __syncthreads();
        for (int i = gs + t; i < ge; i += 256) {
            int v2 = s4[i];
            int pos = gs + atomicAdd(&loff[v2 & 511], 1);
            rows4[pos] = v2 >> 9;
        }
    } else {                                  // k_linc (r9 proven form)
        int local = t >> 6, j = t & 63;
        float Wreg[FDIM];
        #pragma unroll
        for (int k = 0; k < FDIM; ++k) Wreg[k] = W[k * FDIM + j];
        float bj = bvec[j];
        int gw = (b - P) * 4 + local;
        int nwl = GPLIN * 4;
        int slab = j >> 5, jo = j & 31;
        for (int w = gw; w < n; w += nwl) {
            sIn[local][j] = (j < 32) ? x[(size_t)w * 32 + j]
                                     : feat[(size_t)w * 32 + (j - 32)];
            __threadfence_block();
            float o = bj;
            #pragma unroll
            for (int k4 = 0; k4 < 16; ++k4) {
                float4 h4 = *(const float4*)&sIn[local][k4 * 4];
                o = fmaf(h4.x, Wreg[4 * k4 + 0], o);
                o = fmaf(h4.y, Wreg[4 * k4 + 1], o);
                o = fmaf(h4.z, Wreg[4 * k4 + 2], o);
                o = fmaf(h4.w, Wreg[4 * k4 + 3], o);
            }
            g1[(size_t)slab * n * 32 + (size_t)w * 32 + jo] =
                __float2bfloat16(dis[w] * o);
            __threadfence_block();
        }
    }
}

// --- slabbed gather: a[w][j] = relu(dis[w]*(g[w][j]+Σ g[r][j])), bf16 out.
// g,a layout: [2][n][32] (feature slabs). Pass p = slab p; per-XCD working
// set 6.4 MB -> L2-resident-ish. Wave = 1 target; lane = (edge_sub<<2)|fq,
// v8s load covers 8 features of 1 edge -> 16 edges per VMEM instruction.
__global__ __launch_bounds__(256, 8)
void k_gather(const int* __restrict__ rows4, const int* __restrict__ off,
              const float* __restrict__ dis, const bf16* __restrict__ g,
              bf16* __restrict__ a, int n, int nb0) {
    int b = blockIdx.x;
    int pass = (b >= nb0) ? 1 : 0;
    int wv = (b - pass * nb0) * 4 + (threadIdx.x >> 6);
    if (wv >= n) return;
    int lane = threadIdx.x & 63;
    int fq = lane & 3;          // feature quad: features fq*8 .. fq*8+7
    int es = lane >> 2;         // edge sub-slot 0..15
    const bf16* gs = g + (size_t)pass * n * 32;
    bf16* as = a + (size_t)pass * n * 32;
    float acc[8];
    #pragma unroll
    for (int q = 0; q < 8; ++q) acc[q] = 0.0f;
    int s = off[wv], e = off[wv + 1];
    for (int k = s; k < e; k += 16) {
        int idx = k + es;
        // invalid slots clamp to a duplicate row -> coalesced, zero-weighted
        int r = __builtin_nontemporal_load(rows4 + min(idx, e - 1));
        v8s hv = *(const v8s*)&gs[(size_t)r * 32 + fq * 8];
        float wgt = (idx < e) ? 1.0f : 0.0f;
        #pragma unroll
        for (int q = 0; q < 8; ++q) acc[q] = fmaf(wgt, b2f(hv[q]), acc[q]);
    }
    // butterfly-reduce across the 16 edge slots (stride 4,8,16,32)
    #pragma unroll
    for (int m = 4; m <= 32; m <<= 1) {
        #pragma unroll
        for (int q = 0; q < 8; ++q) acc[q] += __shfl_xor(acc[q], m, 64);
    }
    if (es == 0) {
        v8s sv = *(const v8s*)&gs[(size_t)wv * 32 + fq * 8];   // self loop
        float dv = dis[wv];
        v8s ov;
        #pragma unroll
        for (int q = 0; q < 8; ++q)
            ov[q] = f2b(fmaxf(dv * (acc[q] + b2f(sv[q])), 0.0f));
        __builtin_nontemporal_store(ov, (v8s*)&as[(size_t)wv * 32 + fq * 8]);
    }
}

// --- MFMA matvec: o = A@W + b ; FINAL ? relu(o) f32 : slabbed bf16(dis*o) ---
// A layout: [2][n][32] slabs; K-split at 32 aligns with the slab boundary:
// af0 = features 0..31 (lo slab), af1 = features 32..63 (hi slab).
// Layouts (guide-verified): A-frag A[m=lane&15][k=quad*8+j];
// B-frag B[k=quad*8+j][n=lane&15]; C/D: n=lane&15, m=quad*4+reg.
template <bool FINAL>
__global__ __launch_bounds__(256, 4)
void k_mat(const bf16* __restrict__ A, const float* __restrict__ W,
           const float* __restrict__ bvec, const float* __restrict__ dis,
           void* __restrict__ outp, int n) {
    __shared__ __align__(16) bf16 sWt[FDIM * FDIM];   // Wt[n][k] (transposed)
    int t = threadIdx.x;
    for (int idx = t; idx < FDIM * FDIM; idx += 256) {
        int kk = idx >> 6, nn = idx & 63;
        sWt[nn * FDIM + kk] = __float2bfloat16(W[idx]);
    }
    __syncthreads();
    int wave = t >> 6, lane = t & 63;
    int quad = lane >> 4, l15 = lane & 15;
    v8s bfr[4][2];
    #pragma unroll
    for (int nt = 0; nt < 4; ++nt) {
        #pragma unroll
        for (int kf = 0; kf < 2; ++kf)
            bfr[nt][kf] = *(const v8s*)&sWt[(nt * 16 + l15) * FDIM + kf * 32 + quad * 8];
    }
    float bj[4];
    #pragma unroll
    for (int nt = 0; nt < 4; ++nt) bj[nt] = bvec[nt * 16 + l15];

    const bf16* Alo = A;
    const bf16* Ahi = A + (size_t)n * 32;

    int ntiles = (n + 15) >> 4;
    int step = gridDim.x * 4;
    for (int tile = blockIdx.x * 4 + wave; tile < ntiles; tile += step) {
        int m0 = tile << 4;
        int mA = m0 + l15; if (mA >= n) mA = n - 1;
        v8s af0 = *(const v8s*)&Alo[(size_t)mA * 32 + quad * 8];
        v8s af1 = *(const v8s*)&Ahi[(size_t)mA * 32 + quad * 8];
        v4f acc[4];
        #pragma unroll
        for (int nt = 0; nt < 4; ++nt) {
            acc[nt] = (v4f){0.f, 0.f, 0.f, 0.f};
            acc[nt] = __builtin_amdgcn_mfma_f32_16x16x32_bf16(af0, bfr[nt][0], acc[nt], 0, 0, 0);
            acc[nt] = __builtin_amdgcn_mfma_f32_16x16x32_bf16(af1, bfr[nt][1], acc[nt], 0, 0, 0);
        }
        #pragma unroll
        for (int r = 0; r < 4; ++r) {
            int node = m0 + quad * 4 + r;
            if (node >= n) continue;
            float dv = FINAL ? 0.0f : dis[node];
            #pragma unroll
            for (int nt = 0; nt < 4; ++nt) {
                int j = nt * 16 + l15;
                float o = acc[nt][r] + bj[nt];
                if (FINAL) {
                    ((float*)outp)[(size_t)node * FDIM + j] = fmaxf(o, 0.0f);
                } else {
                    ((bf16*)outp)[(size_t)(j >> 5) * n * 32 + (size_t)node * 32 + (j & 31)] =
                        __float2bfloat16(dv * o);
                }
            }
        }
    }
}

extern "C" void kernel_launch(void* const* d_in, const int* in_sizes, int n_in,
                              void* d_out, int out_size, void* d_ws, size_t ws_size,
                              hipStream_t stream) {
    const float* x    = (const float*)d_in[0];
    const float* feat = (const float*)d_in[1];
    const int*   ei   = (const int*)d_in[2];
    const float* W1   = (const float*)d_in[3];
    const float* b1   = (const float*)d_in[4];
    const float* W2   = (const float*)d_in[5];
    const float* b2   = (const float*)d_in[6];
    const float* Wfc  = (const float*)d_in[7];
    const float* bfc  = (const float*)d_in[8];
    float* out = (float*)d_out;

    const int n = in_sizes[0] / 32;   // 100000
    const int E = in_sizes[2] / 2;    // 1600000
    const int* row = ei;
    const int* col = ei + E;

    const int psize = (n + NPART - 1) / NPART;   // 12500
    const int P  = (n + BW - 1) / BW;            // 196
    const int CH = (E + NB - 1) / NB;            // 6250
    const int total = P * NB;                    // 50176
    const int ndis = (n + 255) / 256;            // 391

    // ws: off[n+1] | dis[n] | M[total] | bsum[256] | s4[E] | rows4[E]
    //     | (16B-aligned) bufA(bf16 64n) | bufB(bf16 64n)
    // part (512*psize u32 = 25.6 MB) aliases bufA+bufB (consumed in k_ds1
    // before k_fl writes bufA).
    int*   off  = (int*)d_ws;
    float* dis  = (float*)(off + (size_t)n + 1);
    int*   M    = (int*)(dis + n);
    int*   bsum = M + (size_t)total;
    int*   s4    = bsum + 256;
    int*   rows4 = s4 + E;
    size_t co = (size_t)(rows4 + E - (int*)d_ws);
    co = (co + 3) & ~(size_t)3;                  // 16B align for v8s loads
    bf16*  bufA  = (bf16*)((int*)d_ws + co);
    bf16*  bufB  = bufA + (size_t)n * FDIM;
    unsigned* part = (unsigned*)bufA;

    const int B = 256;
    const int nb0 = (n + 3) / 4;                 // gather blocks per pass

    k_h<<<NPART * GPB + NB, B, 0, stream>>>(row, col, part, M, E, n, psize, P, CH);
    k_ds1<<<ndis + P, B, 0, stream>>>(part, dis, M, bsum, n, psize, ndis, P);
    k_csc<<<NB, B, 0, stream>>>(row, col, M, bsum, s4, E, CH, P);
    k_fl<<<P + GPLIN, B, 0, stream>>>(s4, M, bsum, rows4, off,
                                      x, feat, W1, b1, dis, bufA, n, E, P);
    // layer 2: gather(g1)->a1 ; mat: g2 = bf16(dis*(a1@W2+b2))
    k_gather<<<2 * nb0, B, 0, stream>>>(rows4, off, dis, bufA, bufB, n, nb0);
    k_mat<false><<<512, B, 0, stream>>>(bufB, W2, b2, dis, bufA, n);
    // fc: gather(g2)->a2 ; out = relu(a2@Wfc+bfc)
    k_gather<<<2 * nb0, B, 0, stream>>>(rows4, off, dis, bufA, bufB, n, nb0);
    k_mat<true><<<512, B, 0, stream>>>(bufB, Wfc, bfc, dis, out, n);
}

// Round 4
// 298.293 us; speedup vs baseline: 1.2385x; 1.2385x over previous
//
#include <hip/hip_runtime.h>
#include <hip/hip_bf16.h>

// GCN v14 — v12 base (proven 315 us) + dual-edge gather.
//   r13 post-mortem: slab gather regressed (59.5->89.8 us) — MLP collapsed
//   to ~1 load in flight (serial rows4->v8s chain, ~1.4 iters/node) and
//   16-edge chunk clamp wasted ~43% slots. Slab L2-residency gain was ~nil
//   (148 vs 156 MB FETCH): 6.4 MB/pass still > 4 MB L2 + dirty-write lines.
//   v14 theory: v12 gather is VMEM-issue-limited (128 B/instr; r5's f32
//   gather at 256 B/instr sustained 3.75 TB/s vs v12's 2.93). Fix: 2 edges
//   per instruction — half-wave per edge, ushort2 (2 feat) per lane =
//   256 B/instr, 8-deep unroll (16 edges/iter) keeps 8 loads in flight;
//   shfl_xor(32) merges parity accumulators. All else == v12.

#define FDIM 64
#define NPART 8
#define GPB 64
#define NB 256
#define BW 512
#define MAXP 1024
#define GPLIN 1024

typedef __hip_bfloat16 bf16;
typedef short v8s __attribute__((ext_vector_type(8)));
typedef float v4f __attribute__((ext_vector_type(4)));

static __device__ __forceinline__ float ulo2f(unsigned u) {
    union { unsigned x; float f; } v; v.x = u << 16; return v.f;
}
static __device__ __forceinline__ float uhi2f(unsigned u) {
    union { unsigned x; float f; } v; v.x = u & 0xFFFF0000u; return v.f;
}
static __device__ __forceinline__ unsigned f2bu(float f) {
    bf16 b = __float2bfloat16(f);
    return (unsigned)(*(unsigned short*)&b);
}

// --- dispatch 1: deg partial histograms ∥ coarse col histogram ---
__global__ void k_h(const int* __restrict__ row, const int* __restrict__ col,
                    unsigned* __restrict__ part, int* __restrict__ M,
                    int E, int n, int psize, int P, int CH) {
    __shared__ unsigned sm[12512];
    int t = threadIdx.x, b = blockIdx.x;
    if (b < NPART * GPB) {
        int p = b >> 6, g = b & 63;
        int base = p * psize;
        int lim = n - base; if (lim > psize) lim = psize;
        for (int i = t; i < lim; i += 256) sm[i] = 0u;
        __syncthreads();
        for (int e = g * 256 + t; e < E; e += GPB * 256) {
            int r = row[e] - base;
            if ((unsigned)r < (unsigned)lim) atomicAdd(&sm[r], 1u);
        }
        __syncthreads();
        unsigned* dst = part + ((size_t)p * GPB + g) * psize;
        for (int i = t; i < lim; i += 256) dst[i] = sm[i];
    } else {
        int cb = b - NPART * GPB;
        int* h = (int*)sm;
        for (int i = t; i < P; i += 256) h[i] = 0;
        __syncthreads();
        int s = cb * CH, e = min(s + CH, E);
        for (int i = s + t; i < e; i += 256)
            atomicAdd(&h[col[i] >> 9], 1);
        __syncthreads();
        for (int p = t; p < P; p += 256) M[p * NB + cb] = h[p];
    }
}

// --- dispatch 2: dis ∥ scan pass 1 ---
__global__ void k_ds1(const unsigned* __restrict__ part, float* __restrict__ dis,
                      int* __restrict__ M, int* __restrict__ bsum,
                      int n, int psize, int ndis, int P) {
    __shared__ int sc[256];
    int t = threadIdx.x, b = blockIdx.x;
    if (b < ndis) {
        int i = b * 256 + t;
        if (i >= n) return;
        int p = i / psize, loc = i - p * psize;
        const unsigned* src = part + (size_t)p * GPB * psize + loc;
        unsigned s = 0;
        #pragma unroll 8
        for (int g = 0; g < GPB; ++g) s += src[(size_t)g * psize];
        dis[i] = rsqrtf((float)s + 1.0f);
    } else {
        int sb = b - ndis;
        int i = sb * 256 + t;
        int v = M[i];
        sc[t] = v;
        __syncthreads();
        for (int d = 1; d < 256; d <<= 1) {
            int u = (t >= d) ? sc[t - d] : 0;
            __syncthreads(); sc[t] += u; __syncthreads();
        }
        M[i] = sc[t] - v;
        if (t == 255) bsum[sb] = sc[255];
    }
}

// --- dispatch 3: coarse scatter (inline bsum scan) ---
__global__ void k_csc(const int* __restrict__ row, const int* __restrict__ col,
                      const int* __restrict__ M, const int* __restrict__ bsum,
                      int* __restrict__ s4, int E, int CH, int P) {
    __shared__ int sc[256];
    __shared__ int bs[256];
    __shared__ int cur[MAXP];
    int t = threadIdx.x, b = blockIdx.x;
    int v = (t < P) ? bsum[t] : 0;
    sc[t] = v;
    __syncthreads();
    for (int d = 1; d < 256; d <<= 1) {
        int u = (t >= d) ? sc[t - d] : 0;
        __syncthreads(); sc[t] += u; __syncthreads();
    }
    bs[t] = sc[t] - v;
    __syncthreads();
    for (int p = t; p < P; p += 256) cur[p] = bs[p] + M[p * NB + b];
    __syncthreads();
    int s = b * CH, e = min(s + CH, E);
    for (int i = s + t; i < e; i += 256) {
        int r = row[i], c = col[i];
        int pos = atomicAdd(&cur[c >> 9], 1);
        s4[pos] = (r << 9) | (c & 511);
    }
}

// --- dispatch 4: fine sort (blocks < P) ∥ k_linc (blocks >= P) ---
__global__ __launch_bounds__(256, 4)
void k_fl(const int* __restrict__ s4, const int* __restrict__ M,
          const int* __restrict__ bsum, int* __restrict__ rows4,
          int* __restrict__ off,
          const float* __restrict__ x, const float* __restrict__ feat,
          const float* __restrict__ W, const float* __restrict__ bvec,
          const float* __restrict__ dis, bf16* __restrict__ g1,
          int n, int E, int P) {
    __shared__ int sc[256];
    __shared__ int bs[256];
    __shared__ int hist[BW];
    __shared__ int loff[BW];
    __shared__ int tmp[256];
    __shared__ float sIn[4][FDIM];
    int t = threadIdx.x, b = blockIdx.x;
    if (b < P) {
        int v = (t < P) ? bsum[t] : 0;
        sc[t] = v;
        __syncthreads();
        for (int d = 1; d < 256; d <<= 1) {
            int u = (t >= d) ? sc[t - d] : 0;
            __syncthreads(); sc[t] += u; __syncthreads();
        }
        bs[t] = sc[t] - v;
        __syncthreads();
        int gs = bs[b];
        int ge = gs + bsum[b];
        int c0 = b << 9;
        int lim = n - c0; if (lim > BW) lim = BW;
        hist[2 * t] = 0; hist[2 * t + 1] = 0;
        __syncthreads();
        for (int i = gs + t; i < ge; i += 256)
            atomicAdd(&hist[s4[i] & 511], 1);
        __syncthreads();
        int s0 = hist[2 * t], s1v = hist[2 * t + 1];
        int ps = s0 + s1v;
        tmp[t] = ps;
        __syncthreads();
        for (int d = 1; d < 256; d <<= 1) {
            int u = (t >= d) ? tmp[t - d] : 0;
            __syncthreads(); tmp[t] += u; __syncthreads();
        }
        int ex = tmp[t] - ps;
        loff[2 * t] = ex;
        loff[2 * t + 1] = ex + s0;
        __syncthreads();
        for (int i = t; i < lim; i += 256) off[c0 + i] = gs + loff[i];
        if (b == P - 1 && t == 0) off[n] = E;
        __syncthreads();
        for (int i = gs + t; i < ge; i += 256) {
            int v2 = s4[i];
            int pos = gs + atomicAdd(&loff[v2 & 511], 1);
            rows4[pos] = v2 >> 9;
        }
    } else {                                  // k_linc (r9 proven form)
        int local = t >> 6, j = t & 63;
        float Wreg[FDIM];
        #pragma unroll
        for (int k = 0; k < FDIM; ++k) Wreg[k] = W[k * FDIM + j];
        float bj = bvec[j];
        int gw = (b - P) * 4 + local;
        int nwl = GPLIN * 4;
        for (int w = gw; w < n; w += nwl) {
            sIn[local][j] = (j < 32) ? x[(size_t)w * 32 + j]
                                     : feat[(size_t)w * 32 + (j - 32)];
            __threadfence_block();
            float o = bj;
            #pragma unroll
            for (int k4 = 0; k4 < 16; ++k4) {
                float4 h4 = *(const float4*)&sIn[local][k4 * 4];
                o = fmaf(h4.x, Wreg[4 * k4 + 0], o);
                o = fmaf(h4.y, Wreg[4 * k4 + 1], o);
                o = fmaf(h4.z, Wreg[4 * k4 + 2], o);
                o = fmaf(h4.w, Wreg[4 * k4 + 3], o);
            }
            g1[(size_t)w * FDIM + j] = __float2bfloat16(dis[w] * o);
            __threadfence_block();
        }
    }
}

// --- dual-edge gather: a[w][j] = relu(dis[w]*(g[w][j]+Σ g[r][j])), bf16 out.
// Wave = 1 node. Lane (h=lane>>5, j2=lane&31): half-wave h carries edge
// slot parity h, each lane loads ushort2 (features 2j2, 2j2+1) -> one
// instruction covers 2 full 128-B rows (256 B). 8-deep unroll = 16 edges
// per iteration, 8 g-loads in flight (v12's MLP preserved). Tail via
// clamp-to-(e-1) + zero weight (dup loads hit the already-fetched line).
__global__ __launch_bounds__(256, 8)
void k_gather(const int* __restrict__ rows4, const int* __restrict__ off,
              const float* __restrict__ dis, const bf16* __restrict__ g,
              bf16* __restrict__ a, int n) {
    int t = blockIdx.x * blockDim.x + threadIdx.x;
    int w = t >> 6;
    if (w >= n) return;
    int lane = threadIdx.x & 63;
    int h = lane >> 5;          // edge-slot parity
    int j2 = lane & 31;         // feature pair index
    const unsigned* g32 = (const unsigned*)g;   // one row = 32 uints
    float acc0 = 0.0f, acc1 = 0.0f;
    int s = off[w], e = off[w + 1];
    for (int k = s; k < e; k += 16) {
        #pragma unroll
        for (int i = 0; i < 8; ++i) {
            int idx = k + 2 * i + h;
            int r = rows4[min(idx, e - 1)];
            unsigned u = g32[(size_t)r * 32 + j2];
            float wg = (idx < e) ? 1.0f : 0.0f;
            acc0 = fmaf(wg, ulo2f(u), acc0);
            acc1 = fmaf(wg, uhi2f(u), acc1);
        }
    }
    acc0 += __shfl_xor(acc0, 32, 64);
    acc1 += __shfl_xor(acc1, 32, 64);
    if (h == 0) {
        unsigned su = g32[(size_t)w * 32 + j2];    // self loop
        float dv = dis[w];
        float v0 = fmaxf(dv * (acc0 + ulo2f(su)), 0.0f);
        float v1 = fmaxf(dv * (acc1 + uhi2f(su)), 0.0f);
        ((unsigned*)a)[(size_t)w * 32 + j2] = f2bu(v0) | (f2bu(v1) << 16);
    }
}

// --- MFMA matvec: o = A@W + b ; FINAL ? relu(o) f32 : bf16(dis*o) ---
// Layouts (guide-verified): A-frag A[m=lane&15][k=quad*8+j];
// B-frag B[k=quad*8+j][n=lane&15]; C/D: n=lane&15, m=quad*4+reg.
template <bool FINAL>
__global__ __launch_bounds__(256, 4)
void k_mat(const bf16* __restrict__ A, const float* __restrict__ W,
           const float* __restrict__ bvec, const float* __restrict__ dis,
           void* __restrict__ outp, int n) {
    __shared__ __align__(16) bf16 sWt[FDIM * FDIM];   // Wt[n][k] (transposed)
    int t = threadIdx.x;
    for (int idx = t; idx < FDIM * FDIM; idx += 256) {
        int kk = idx >> 6, nn = idx & 63;
        sWt[nn * FDIM + kk] = __float2bfloat16(W[idx]);
    }
    __syncthreads();
    int wave = t >> 6, lane = t & 63;
    int quad = lane >> 4, l15 = lane & 15;
    v8s bfr[4][2];
    #pragma unroll
    for (int nt = 0; nt < 4; ++nt) {
        #pragma unroll
        for (int kf = 0; kf < 2; ++kf)
            bfr[nt][kf] = *(const v8s*)&sWt[(nt * 16 + l15) * FDIM + kf * 32 + quad * 8];
    }
    float bj[4];
    #pragma unroll
    for (int nt = 0; nt < 4; ++nt) bj[nt] = bvec[nt * 16 + l15];

    int ntiles = (n + 15) >> 4;
    int step = gridDim.x * 4;
    for (int tile = blockIdx.x * 4 + wave; tile < ntiles; tile += step) {
        int m0 = tile << 4;
        int mA = m0 + l15; if (mA >= n) mA = n - 1;
        v8s af0 = *(const v8s*)&A[(size_t)mA * FDIM + quad * 8];
        v8s af1 = *(const v8s*)&A[(size_t)mA * FDIM + 32 + quad * 8];
        v4f acc[4];
        #pragma unroll
        for (int nt = 0; nt < 4; ++nt) {
            acc[nt] = (v4f){0.f, 0.f, 0.f, 0.f};
            acc[nt] = __builtin_amdgcn_mfma_f32_16x16x32_bf16(af0, bfr[nt][0], acc[nt], 0, 0, 0);
            acc[nt] = __builtin_amdgcn_mfma_f32_16x16x32_bf16(af1, bfr[nt][1], acc[nt], 0, 0, 0);
        }
        #pragma unroll
        for (int r = 0; r < 4; ++r) {
            int node = m0 + quad * 4 + r;
            if (node >= n) continue;
            float dv = FINAL ? 0.0f : dis[node];
            #pragma unroll
            for (int nt = 0; nt < 4; ++nt) {
                int j = nt * 16 + l15;
                float o = acc[nt][r] + bj[nt];
                if (FINAL) ((float*)outp)[(size_t)node * FDIM + j] = fmaxf(o, 0.0f);
                else ((bf16*)outp)[(size_t)node * FDIM + j] = __float2bfloat16(dv * o);
            }
        }
    }
}

extern "C" void kernel_launch(void* const* d_in, const int* in_sizes, int n_in,
                              void* d_out, int out_size, void* d_ws, size_t ws_size,
                              hipStream_t stream) {
    const float* x    = (const float*)d_in[0];
    const float* feat = (const float*)d_in[1];
    const int*   ei   = (const int*)d_in[2];
    const float* W1   = (const float*)d_in[3];
    const float* b1   = (const float*)d_in[4];
    const float* W2   = (const float*)d_in[5];
    const float* b2   = (const float*)d_in[6];
    const float* Wfc  = (const float*)d_in[7];
    const float* bfc  = (const float*)d_in[8];
    float* out = (float*)d_out;

    const int n = in_sizes[0] / 32;   // 100000
    const int E = in_sizes[2] / 2;    // 1600000
    const int* row = ei;
    const int* col = ei + E;

    const int psize = (n + NPART - 1) / NPART;   // 12500
    const int P  = (n + BW - 1) / BW;            // 196
    const int CH = (E + NB - 1) / NB;            // 6250
    const int total = P * NB;                    // 50176
    const int ndis = (n + 255) / 256;            // 391

    // ws: off[n+1] | dis[n] | M[total] | bsum[256] | s4[E] | rows4[E]
    //     | (16B-aligned) bufA(bf16 64n) | bufB(bf16 64n)
    // part (512*psize u32 = 25.6 MB) aliases bufA+bufB (consumed in k_ds1
    // before k_fl writes bufA).
    int*   off  = (int*)d_ws;
    float* dis  = (float*)(off + (size_t)n + 1);
    int*   M    = (int*)(dis + n);
    int*   bsum = M + (size_t)total;
    int*   s4    = bsum + 256;
    int*   rows4 = s4 + E;
    size_t co = (size_t)(rows4 + E - (int*)d_ws);
    co = (co + 3) & ~(size_t)3;                  // 16B align for v8s loads
    bf16*  bufA  = (bf16*)((int*)d_ws + co);
    bf16*  bufB  = bufA + (size_t)n * FDIM;
    unsigned* part = (unsigned*)bufA;

    const int B = 256;

    k_h<<<NPART * GPB + NB, B, 0, stream>>>(row, col, part, M, E, n, psize, P, CH);
    k_ds1<<<ndis + P, B, 0, stream>>>(part, dis, M, bsum, n, psize, ndis, P);
    k_csc<<<NB, B, 0, stream>>>(row, col, M, bsum, s4, E, CH, P);
    k_fl<<<P + GPLIN, B, 0, stream>>>(s4, M, bsum, rows4, off,
                                      x, feat, W1, b1, dis, bufA, n, E, P);
    // layer 2: gather(g1)->a1 ; mat: g2 = bf16(dis*(a1@W2+b2))
    k_gather<<<(n + 3) / 4, B, 0, stream>>>(rows4, off, dis, bufA, bufB, n);
    k_mat<false><<<512, B, 0, stream>>>(bufB, W2, b2, dis, bufA, n);
    // fc: gather(g2)->a2 ; out = relu(a2@Wfc+bfc)
    k_gather<<<(n + 3) / 4, B, 0, stream>>>(rows4, off, dis, bufA, bufB, n);
    k_mat<true><<<512, B, 0, stream>>>(bufB, Wfc, bfc, dis, out, n);
}